// Round 1
// baseline (6901.389 us; speedup 1.0000x reference)
//
#include <hip/hip_runtime.h>
#include <math.h>

// GnrlPatSoftmaxRNN: chunked low-rank reformulation.
// Within a chunk of TC steps:  pat_t = S_t[p]*pat_t0[p,:] + S_t[p]*sum_s v_s[p]*h_s[:]
// with analytic per-step norm  n = sqrt(d^2 + 2 d pr raw + pr^2 ||h||^2) + 1e-10
// raw_i[p] = S[p]*(R0[i,p] + sum_{s<i} v_s[p]*G[s,i]);  q_i = pr_i * S_{i-1}
// new_h_i  = sum_p q_i[p]*pat_t0[p,:] + sum_{s<i} (q_i . v_s) * h_s
// pat is stored UNNORMALIZED after each chunk materialization; 1/norm is folded
// multiplicatively into R0, q, S downstream (never an extra pass over pat).

#define T_TOT 256
#define NB    64
#define NP    1024
#define NH    512
#define TC    16
#define NCH   (T_TOT / TC)
#define DECAYF 0.999f

// ---------------------------------------------------------------- kG: Gram per chunk
__global__ __launch_bounds__(256) void kG(const float* __restrict__ x, float* __restrict__ G_all) {
    int c = blockIdx.x, b = blockIdx.y, tid = threadIdx.x;
    __shared__ float4 hs[TC][NH / 4 + 1];  // +1 float4 pad -> row stride 516 floats (bank spread)
    for (int idx = tid; idx < TC * (NH / 4); idx += 256) {
        int s = idx / (NH / 4), g = idx % (NH / 4);
        hs[s][g] = ((const float4*)x)[(size_t)((c * TC + s) * NB + b) * (NH / 4) + g];
    }
    __syncthreads();
    int si = tid / TC, ii = tid % TC;
    float acc = 0.f;
    for (int g = 0; g < NH / 4; g++) {
        float4 a = hs[si][g], bb = hs[ii][g];
        acc += a.x * bb.x + a.y * bb.y + a.z * bb.z + a.w * bb.w;
    }
    G_all[(size_t)((c * NB + b) * TC + si) * TC + ii] = acc;
}

// ---------------------------------------------------------------- kInit: copy pat + R0 for chunk 0
__global__ __launch_bounds__(256) void kInit(const float* __restrict__ patin, float* __restrict__ pat,
                                             const float* __restrict__ x, float* __restrict__ R0,
                                             float* __restrict__ inr_g) {
    int b = blockIdx.y, tid = threadIdx.x;
    int p = blockIdx.x * 256 + tid;
    __shared__ float4 hn[TC][NH / 4];
    for (int idx = tid; idx < TC * (NH / 4); idx += 256) {
        int s = idx / (NH / 4), g = idx % (NH / 4);
        hn[s][g] = ((const float4*)x)[(size_t)(s * NB + b) * (NH / 4) + g];
    }
    __syncthreads();
    const float4* pin = ((const float4*)patin) + (size_t)(b * NP + p) * (NH / 4);
    float4* pout = ((float4*)pat) + (size_t)(b * NP + p) * (NH / 4);
    float r0[TC];
#pragma unroll
    for (int i = 0; i < TC; i++) r0[i] = 0.f;
    for (int g = 0; g < NH / 4; g++) {
        float4 pv = pin[g];
#pragma unroll
        for (int i = 0; i < TC; i++) {
            float4 nv = hn[i][g];
            r0[i] += pv.x * nv.x + pv.y * nv.y + pv.z * nv.z + pv.w * nv.w;
        }
        pout[g] = pv;
    }
    inr_g[b * NP + p] = 1.0f;
#pragma unroll
    for (int i = 0; i < TC; i++) R0[(size_t)(b * TC + i) * NP + p] = r0[i];
}

// ---------------------------------------------------------------- kInner: 16 sequential steps
__global__ __launch_bounds__(256, 1) void kInner(const float* __restrict__ R0, const float* __restrict__ G_all,
                                                 const float* __restrict__ inr_g, float* __restrict__ q_g,
                                                 float* __restrict__ wc_g, float* __restrict__ S_g,
                                                 float* __restrict__ Beta_g, int c) {
    int b = blockIdx.x, tid = threadIdx.x;
    __shared__ float Gs[TC * TC];
    __shared__ float redm[TC][4], reds[TC][4];
    __shared__ float betas[TC * TC];
    if (tid < TC * TC) {
        Gs[tid] = G_all[(size_t)(c * NB + b) * TC * TC + tid];
        betas[tid] = 0.f;
    }
    __syncthreads();
    const float* R0b = R0 + (size_t)b * TC * NP;
    // prefetch R0 for all 16 steps (hides L2/L3 latency across the serial chain)
    float r0p[4][TC];
#pragma unroll
    for (int k = 0; k < 4; k++)
#pragma unroll
        for (int i = 0; i < TC; i++) r0p[k][i] = R0b[(size_t)i * NP + tid + 256 * k];

    float S[4] = {1.f, 1.f, 1.f, 1.f};
    float v[4][TC], q[4][TC];
    int wid = tid >> 6, lane = tid & 63;
    float raw[4];
#pragma unroll
    for (int i = 0; i < TC; i++) {
        float mymax = -1e30f;
#pragma unroll
        for (int k = 0; k < 4; k++) {
            float acc = r0p[k][i];
#pragma unroll
            for (int s = 0; s < i; s++) acc += v[k][s] * Gs[s * TC + i];
            raw[k] = S[k] * acc;
            mymax = fmaxf(mymax, raw[k]);
        }
#pragma unroll
        for (int o = 32; o > 0; o >>= 1) mymax = fmaxf(mymax, __shfl_xor(mymax, o, 64));
        if (lane == 0) redm[i][wid] = mymax;
        __syncthreads();
        float m = fmaxf(fmaxf(redm[i][0], redm[i][1]), fmaxf(redm[i][2], redm[i][3]));
        float hh = Gs[i * TC + i];
        float e[4], esum = 0.f;
#pragma unroll
        for (int k = 0; k < 4; k++) {
            float lg = (raw[k] >= 0.9f * m) ? (raw[k] / m) * 10.0f : 0.0f;
            e[k] = __expf(lg - 10.0f);  // max logit is exactly 10
            esum += e[k];
        }
#pragma unroll
        for (int o = 32; o > 0; o >>= 1) esum += __shfl_xor(esum, o, 64);
        if (lane == 0) reds[i][wid] = esum;
        __syncthreads();
        float dinv = 1.0f / (reds[i][0] + reds[i][1] + reds[i][2] + reds[i][3]);
#pragma unroll
        for (int k = 0; k < 4; k++) {
            float pr = e[k] * dinv;
            q[k][i] = pr * S[k];                      // uses S_{i-1}
            float nn = sqrtf(DECAYF * DECAYF + 2.0f * DECAYF * pr * raw[k] + pr * pr * hh) + 1e-10f;
            v[k][i] = pr / (DECAYF * S[k]);           // = W_ii / S_i  (n cancels)
            S[k] = S[k] * (DECAYF / nn);
        }
    }
    // epilogue: fold 1/norm of stored pat_t0 into q (vs stored pat) and S; wc stays in true-h coords
#pragma unroll
    for (int k = 0; k < 4; k++) {
        int p = tid + 256 * k;
        float inr = inr_g[b * NP + p];
#pragma unroll
        for (int i = 0; i < TC; i++) {
            q_g[(size_t)(b * TC + i) * NP + p] = q[k][i] * inr;
            wc_g[(size_t)(b * TC + i) * NP + p] = S[k] * v[k][i];
        }
        S_g[b * NP + p] = S[k] * inr;
    }
    // Beta[i][s] = sum_p q_i[p] * v_s[p]  (raw q: multiplies true h_s, not stored pat)
#pragma unroll
    for (int i = 1; i < TC; i++)
#pragma unroll
        for (int s = 0; s < i; s++) {
            float part = q[0][i] * v[0][s] + q[1][i] * v[1][s] + q[2][i] * v[2][s] + q[3][i] * v[3][s];
            atomicAdd(&betas[i * TC + s], part);
        }
    __syncthreads();
    if (tid < TC * TC) {
        int i = tid / TC, s = tid % TC;
        Beta_g[(size_t)b * TC * TC + tid] = (s < i) ? betas[tid] : 0.f;
    }
}

// ---------------------------------------------------------------- kOut: out = Q*pat_t0 + Beta*Hc
__global__ __launch_bounds__(256) void kOut(const float* __restrict__ pat, const float* __restrict__ x,
                                            const float* __restrict__ q_g, const float* __restrict__ Beta_g,
                                            float* __restrict__ out, int c) {
    int b = blockIdx.y, ht = blockIdx.x, tid = threadIdx.x;
    int lane = tid & 63, iq = tid >> 6;
    int h = ht * 64 + lane;
    __shared__ float qsh[TC][NP];  // 64 KB
    __shared__ float betash[TC * TC];
    for (int idx = tid; idx < TC * NP; idx += 256) qsh[idx >> 10][idx & 1023] = q_g[(size_t)b * TC * NP + idx];
    betash[tid] = Beta_g[(size_t)b * TC * TC + tid];
    __syncthreads();
    float acc[4] = {0.f, 0.f, 0.f, 0.f};
    const float* patb = pat + (size_t)b * NP * NH + h;
#pragma unroll 4
    for (int p = 0; p < NP; p++) {
        float pv = patb[(size_t)p * NH];
#pragma unroll
        for (int j = 0; j < 4; j++) acc[j] += qsh[iq * 4 + j][p] * pv;
    }
#pragma unroll
    for (int s = 0; s < TC; s++) {
        float xv = x[(size_t)((c * TC + s) * NB + b) * NH + h];
#pragma unroll
        for (int j = 0; j < 4; j++) {
            int i = iq * 4 + j;
            if (s < i) acc[j] += betash[i * TC + s] * xv;
        }
    }
#pragma unroll
    for (int j = 0; j < 4; j++) out[(size_t)((c * TC + iq * 4 + j) * NB + b) * NH + h] = acc[j];
}

// ---------------------------------------------------------------- kMat: materialize pat + R0(next) + 1/norm
__global__ __launch_bounds__(256, 2) void kMat(float* __restrict__ pat, const float* __restrict__ x,
                                               const float* __restrict__ wc_g, const float* __restrict__ S_g,
                                               float* __restrict__ R0, float* __restrict__ inr_g, int c) {
    int b = blockIdx.y, tid = threadIdx.x;
    int p = blockIdx.x * 256 + tid;
    __shared__ float4 hc[TC][NH / 4];  // current chunk h's (update)
    __shared__ float4 hn[TC][NH / 4];  // next chunk h's (R0)
    for (int idx = tid; idx < TC * (NH / 4); idx += 256) {
        int s = idx / (NH / 4), g = idx % (NH / 4);
        hc[s][g] = ((const float4*)x)[(size_t)((c * TC + s) * NB + b) * (NH / 4) + g];
        hn[s][g] = ((const float4*)x)[(size_t)(((c + 1) * TC + s) * NB + b) * (NH / 4) + g];
    }
    __syncthreads();
    float Sf = S_g[b * NP + p];  // already includes 1/norm of stored pat_t0
    float wc[TC];
#pragma unroll
    for (int s = 0; s < TC; s++) wc[s] = wc_g[(size_t)(b * TC + s) * NP + p];
    float4* prow = ((float4*)pat) + (size_t)(b * NP + p) * (NH / 4);
    float nrm = 0.f;
    float r0[TC];
#pragma unroll
    for (int i = 0; i < TC; i++) r0[i] = 0.f;
#pragma unroll 2
    for (int g = 0; g < NH / 4; g++) {
        float4 pv = prow[g];
        float4 pn;
        pn.x = Sf * pv.x; pn.y = Sf * pv.y; pn.z = Sf * pv.z; pn.w = Sf * pv.w;
#pragma unroll
        for (int s = 0; s < TC; s++) {
            float4 hv = hc[s][g];
            pn.x += wc[s] * hv.x; pn.y += wc[s] * hv.y; pn.z += wc[s] * hv.z; pn.w += wc[s] * hv.w;
        }
        nrm += pn.x * pn.x + pn.y * pn.y + pn.z * pn.z + pn.w * pn.w;
#pragma unroll
        for (int i = 0; i < TC; i++) {
            float4 nv = hn[i][g];
            r0[i] += pn.x * nv.x + pn.y * nv.y + pn.z * nv.z + pn.w * nv.w;
        }
        prow[g] = pn;  // store UNNORMALIZED; 1/norm folded downstream
    }
    float inr = 1.0f / (sqrtf(nrm) + 1e-10f);
    inr_g[b * NP + p] = inr;
#pragma unroll
    for (int i = 0; i < TC; i++) R0[(size_t)(b * TC + i) * NP + p] = r0[i] * inr;
}

// ---------------------------------------------------------------- launch
extern "C" void kernel_launch(void* const* d_in, const int* in_sizes, int n_in,
                              void* d_out, int out_size, void* d_ws, size_t ws_size,
                              hipStream_t stream) {
    const float* x = (const float*)d_in[0];      // [T,B,H]
    const float* patin = (const float*)d_in[1];  // [B,P,H]
    float* out = (float*)d_out;                  // [T,B,H]

    char* ws = (char*)d_ws;
    size_t off = 0;
    auto alloc = [&](size_t nfloats) { float* r = (float*)(ws + off); off += nfloats * sizeof(float); return r; };

    const size_t patN = (size_t)NB * NP * NH;
    const size_t restN = 3ull * NB * TC * NP + 2ull * NB * NP + (size_t)NCH * NB * TC * TC + (size_t)NB * TC * TC;
    float* pat;
    if (ws_size >= (patN + restN) * sizeof(float)) {
        pat = alloc(patN);
    } else {
        pat = (float*)d_in[1];  // fallback: mutate input in place (harness restores pristine copy per launch)
    }
    float* R0 = alloc((size_t)NB * TC * NP);
    float* q_g = alloc((size_t)NB * TC * NP);
    float* wc_g = alloc((size_t)NB * TC * NP);
    float* S_g = alloc((size_t)NB * NP);
    float* inr_g = alloc((size_t)NB * NP);
    float* G_all = alloc((size_t)NCH * NB * TC * TC);
    float* Beta = alloc((size_t)NB * TC * TC);

    kG<<<dim3(NCH, NB), 256, 0, stream>>>(x, G_all);
    kInit<<<dim3(4, NB), 256, 0, stream>>>(patin, pat, x, R0, inr_g);
    for (int c = 0; c < NCH; c++) {
        kInner<<<NB, 256, 0, stream>>>(R0, G_all, inr_g, q_g, wc_g, S_g, Beta, c);
        kOut<<<dim3(8, NB), 256, 0, stream>>>(pat, x, q_g, Beta, out, c);
        if (c + 1 < NCH) kMat<<<dim3(4, NB), 256, 0, stream>>>(pat, x, wc_g, S_g, R0, inr_g, c);
    }
}

// Round 2
// 3963.290 us; speedup vs baseline: 1.7413x; 1.7413x over previous
//
#include <hip/hip_runtime.h>
#include <math.h>

// GnrlPatSoftmaxRNN: chunked low-rank reformulation.
// Within a chunk of TC steps:  pat_t = S_t[p]*pat_t0[p,:] + S_t[p]*sum_s v_s[p]*h_s[:]
// with analytic per-step norm  n = sqrt(d^2 + 2 d pr raw + pr^2 ||h||^2) + 1e-10
// raw_i[p] = S[p]*(R0[i,p] + sum_{s<i} v_s[p]*G[s,i]);  q_i = pr_i * S_{i-1}
// new_h_i  = sum_p q_i[p]*pat_t0[p,:] + sum_{s<i} (q_i . v_s) * h_s
// pat is stored UNNORMALIZED after each chunk materialization; 1/norm is folded
// multiplicatively into R0, q, S downstream (never an extra pass over pat).
//
// R1 post-mortem: kInner was 249us/launch — 256 thr x 120 LDS atomicAdds onto
// 120 addresses = 30720 serialized RMWs (~600k cyc = 250us, matches counter).
// R2: wave-level shfl reduction first, one atomic per wave per (i,s) pair.

#define T_TOT 256
#define NB    64
#define NP    1024
#define NH    512
#define TC    16
#define NCH   (T_TOT / TC)
#define DECAYF 0.999f

// ---------------------------------------------------------------- kG: Gram per chunk
__global__ __launch_bounds__(256) void kG(const float* __restrict__ x, float* __restrict__ G_all) {
    int c = blockIdx.x, b = blockIdx.y, tid = threadIdx.x;
    __shared__ float4 hs[TC][NH / 4 + 1];  // +1 float4 pad -> row stride 516 floats (bank spread)
    for (int idx = tid; idx < TC * (NH / 4); idx += 256) {
        int s = idx / (NH / 4), g = idx % (NH / 4);
        hs[s][g] = ((const float4*)x)[(size_t)((c * TC + s) * NB + b) * (NH / 4) + g];
    }
    __syncthreads();
    int si = tid / TC, ii = tid % TC;
    float acc = 0.f;
    for (int g = 0; g < NH / 4; g++) {
        float4 a = hs[si][g], bb = hs[ii][g];
        acc += a.x * bb.x + a.y * bb.y + a.z * bb.z + a.w * bb.w;
    }
    G_all[(size_t)((c * NB + b) * TC + si) * TC + ii] = acc;
}

// ---------------------------------------------------------------- kInit: copy pat + R0 for chunk 0
__global__ __launch_bounds__(256) void kInit(const float* __restrict__ patin, float* __restrict__ pat,
                                             const float* __restrict__ x, float* __restrict__ R0,
                                             float* __restrict__ inr_g) {
    int b = blockIdx.y, tid = threadIdx.x;
    int p = blockIdx.x * 256 + tid;
    __shared__ float4 hn[TC][NH / 4];
    for (int idx = tid; idx < TC * (NH / 4); idx += 256) {
        int s = idx / (NH / 4), g = idx % (NH / 4);
        hn[s][g] = ((const float4*)x)[(size_t)(s * NB + b) * (NH / 4) + g];
    }
    __syncthreads();
    const float4* pin = ((const float4*)patin) + (size_t)(b * NP + p) * (NH / 4);
    float4* pout = ((float4*)pat) + (size_t)(b * NP + p) * (NH / 4);
    float r0[TC];
#pragma unroll
    for (int i = 0; i < TC; i++) r0[i] = 0.f;
    for (int g = 0; g < NH / 4; g++) {
        float4 pv = pin[g];
#pragma unroll
        for (int i = 0; i < TC; i++) {
            float4 nv = hn[i][g];
            r0[i] += pv.x * nv.x + pv.y * nv.y + pv.z * nv.z + pv.w * nv.w;
        }
        pout[g] = pv;
    }
    inr_g[b * NP + p] = 1.0f;
#pragma unroll
    for (int i = 0; i < TC; i++) R0[(size_t)(b * TC + i) * NP + p] = r0[i];
}

// ---------------------------------------------------------------- kInner: 16 sequential steps
__global__ __launch_bounds__(256, 1) void kInner(const float* __restrict__ R0, const float* __restrict__ G_all,
                                                 const float* __restrict__ inr_g, float* __restrict__ q_g,
                                                 float* __restrict__ wc_g, float* __restrict__ S_g,
                                                 float* __restrict__ Beta_g, int c) {
    int b = blockIdx.x, tid = threadIdx.x;
    __shared__ float Gs[TC * TC];
    __shared__ float redm[TC][4], reds[TC][4];
    __shared__ float betas[TC * TC];
    if (tid < TC * TC) {
        Gs[tid] = G_all[(size_t)(c * NB + b) * TC * TC + tid];
        betas[tid] = 0.f;
    }
    __syncthreads();
    const float* R0b = R0 + (size_t)b * TC * NP;
    // prefetch R0 for all 16 steps (hides L2/L3 latency across the serial chain)
    float r0p[4][TC];
#pragma unroll
    for (int k = 0; k < 4; k++)
#pragma unroll
        for (int i = 0; i < TC; i++) r0p[k][i] = R0b[(size_t)i * NP + tid + 256 * k];

    float S[4] = {1.f, 1.f, 1.f, 1.f};
    float v[4][TC], q[4][TC];
    int wid = tid >> 6, lane = tid & 63;
    float raw[4];
#pragma unroll
    for (int i = 0; i < TC; i++) {
        float mymax = -1e30f;
#pragma unroll
        for (int k = 0; k < 4; k++) {
            float acc = r0p[k][i];
#pragma unroll
            for (int s = 0; s < i; s++) acc += v[k][s] * Gs[s * TC + i];
            raw[k] = S[k] * acc;
            mymax = fmaxf(mymax, raw[k]);
        }
#pragma unroll
        for (int o = 32; o > 0; o >>= 1) mymax = fmaxf(mymax, __shfl_xor(mymax, o, 64));
        if (lane == 0) redm[i][wid] = mymax;
        __syncthreads();
        float m = fmaxf(fmaxf(redm[i][0], redm[i][1]), fmaxf(redm[i][2], redm[i][3]));
        float hh = Gs[i * TC + i];
        float e[4], esum = 0.f;
#pragma unroll
        for (int k = 0; k < 4; k++) {
            float lg = (raw[k] >= 0.9f * m) ? (raw[k] / m) * 10.0f : 0.0f;
            e[k] = __expf(lg - 10.0f);  // max logit is exactly 10
            esum += e[k];
        }
#pragma unroll
        for (int o = 32; o > 0; o >>= 1) esum += __shfl_xor(esum, o, 64);
        if (lane == 0) reds[i][wid] = esum;
        __syncthreads();
        float dinv = 1.0f / (reds[i][0] + reds[i][1] + reds[i][2] + reds[i][3]);
#pragma unroll
        for (int k = 0; k < 4; k++) {
            float pr = e[k] * dinv;
            q[k][i] = pr * S[k];                      // uses S_{i-1}
            float nn = sqrtf(DECAYF * DECAYF + 2.0f * DECAYF * pr * raw[k] + pr * pr * hh) + 1e-10f;
            v[k][i] = pr / (DECAYF * S[k]);           // = W_ii / S_i  (n cancels)
            S[k] = S[k] * (DECAYF / nn);
        }
    }
    // epilogue: fold 1/norm of stored pat_t0 into q (vs stored pat) and S; wc stays in true-h coords
#pragma unroll
    for (int k = 0; k < 4; k++) {
        int p = tid + 256 * k;
        float inr = inr_g[b * NP + p];
#pragma unroll
        for (int i = 0; i < TC; i++) {
            q_g[(size_t)(b * TC + i) * NP + p] = q[k][i] * inr;
            wc_g[(size_t)(b * TC + i) * NP + p] = S[k] * v[k][i];
        }
        S_g[b * NP + p] = S[k] * inr;
    }
    // Beta[i][s] = sum_p q_i[p] * v_s[p]  (raw q: multiplies true h_s, not stored pat)
    // R2: wave-level shfl reduction, then ONE atomicAdd per wave per pair
    // (was: 256 thr x 120 atomics -> 30720 serialized LDS RMWs = 250us/launch)
#pragma unroll
    for (int i = 1; i < TC; i++) {
#pragma unroll
        for (int s = 0; s < i; s++) {
            float part = q[0][i] * v[0][s] + q[1][i] * v[1][s] + q[2][i] * v[2][s] + q[3][i] * v[3][s];
#pragma unroll
            for (int o = 32; o > 0; o >>= 1) part += __shfl_xor(part, o, 64);
            if (lane == 0) atomicAdd(&betas[i * TC + s], part);
        }
    }
    __syncthreads();
    if (tid < TC * TC) {
        int i = tid / TC, s = tid % TC;
        Beta_g[(size_t)b * TC * TC + tid] = (s < i) ? betas[tid] : 0.f;
    }
}

// ---------------------------------------------------------------- kOut: out = Q*pat_t0 + Beta*Hc
__global__ __launch_bounds__(256) void kOut(const float* __restrict__ pat, const float* __restrict__ x,
                                            const float* __restrict__ q_g, const float* __restrict__ Beta_g,
                                            float* __restrict__ out, int c) {
    int b = blockIdx.y, ht = blockIdx.x, tid = threadIdx.x;
    int lane = tid & 63, iq = tid >> 6;
    int h = ht * 64 + lane;
    __shared__ float qsh[TC][NP];  // 64 KB
    __shared__ float betash[TC * TC];
    for (int idx = tid; idx < TC * NP; idx += 256) qsh[idx >> 10][idx & 1023] = q_g[(size_t)b * TC * NP + idx];
    betash[tid] = Beta_g[(size_t)b * TC * TC + tid];
    __syncthreads();
    float acc[4] = {0.f, 0.f, 0.f, 0.f};
    const float* patb = pat + (size_t)b * NP * NH + h;
#pragma unroll 4
    for (int p = 0; p < NP; p++) {
        float pv = patb[(size_t)p * NH];
#pragma unroll
        for (int j = 0; j < 4; j++) acc[j] += qsh[iq * 4 + j][p] * pv;
    }
#pragma unroll
    for (int s = 0; s < TC; s++) {
        float xv = x[(size_t)((c * TC + s) * NB + b) * NH + h];
#pragma unroll
        for (int j = 0; j < 4; j++) {
            int i = iq * 4 + j;
            if (s < i) acc[j] += betash[i * TC + s] * xv;
        }
    }
#pragma unroll
    for (int j = 0; j < 4; j++) out[(size_t)((c * TC + iq * 4 + j) * NB + b) * NH + h] = acc[j];
}

// ---------------------------------------------------------------- kMat: materialize pat + R0(next) + 1/norm
__global__ __launch_bounds__(256, 2) void kMat(float* __restrict__ pat, const float* __restrict__ x,
                                               const float* __restrict__ wc_g, const float* __restrict__ S_g,
                                               float* __restrict__ R0, float* __restrict__ inr_g, int c) {
    int b = blockIdx.y, tid = threadIdx.x;
    int p = blockIdx.x * 256 + tid;
    __shared__ float4 hc[TC][NH / 4];  // current chunk h's (update)
    __shared__ float4 hn[TC][NH / 4];  // next chunk h's (R0)
    for (int idx = tid; idx < TC * (NH / 4); idx += 256) {
        int s = idx / (NH / 4), g = idx % (NH / 4);
        hc[s][g] = ((const float4*)x)[(size_t)((c * TC + s) * NB + b) * (NH / 4) + g];
        hn[s][g] = ((const float4*)x)[(size_t)(((c + 1) * TC + s) * NB + b) * (NH / 4) + g];
    }
    __syncthreads();
    float Sf = S_g[b * NP + p];  // already includes 1/norm of stored pat_t0
    float wc[TC];
#pragma unroll
    for (int s = 0; s < TC; s++) wc[s] = wc_g[(size_t)(b * TC + s) * NP + p];
    float4* prow = ((float4*)pat) + (size_t)(b * NP + p) * (NH / 4);
    float nrm = 0.f;
    float r0[TC];
#pragma unroll
    for (int i = 0; i < TC; i++) r0[i] = 0.f;
#pragma unroll 2
    for (int g = 0; g < NH / 4; g++) {
        float4 pv = prow[g];
        float4 pn;
        pn.x = Sf * pv.x; pn.y = Sf * pv.y; pn.z = Sf * pv.z; pn.w = Sf * pv.w;
#pragma unroll
        for (int s = 0; s < TC; s++) {
            float4 hv = hc[s][g];
            pn.x += wc[s] * hv.x; pn.y += wc[s] * hv.y; pn.z += wc[s] * hv.z; pn.w += wc[s] * hv.w;
        }
        nrm += pn.x * pn.x + pn.y * pn.y + pn.z * pn.z + pn.w * pn.w;
#pragma unroll
        for (int i = 0; i < TC; i++) {
            float4 nv = hn[i][g];
            r0[i] += pn.x * nv.x + pn.y * nv.y + pn.z * nv.z + pn.w * nv.w;
        }
        prow[g] = pn;  // store UNNORMALIZED; 1/norm folded downstream
    }
    float inr = 1.0f / (sqrtf(nrm) + 1e-10f);
    inr_g[b * NP + p] = inr;
#pragma unroll
    for (int i = 0; i < TC; i++) R0[(size_t)(b * TC + i) * NP + p] = r0[i] * inr;
}

// ---------------------------------------------------------------- launch
extern "C" void kernel_launch(void* const* d_in, const int* in_sizes, int n_in,
                              void* d_out, int out_size, void* d_ws, size_t ws_size,
                              hipStream_t stream) {
    const float* x = (const float*)d_in[0];      // [T,B,H]
    const float* patin = (const float*)d_in[1];  // [B,P,H]
    float* out = (float*)d_out;                  // [T,B,H]

    char* ws = (char*)d_ws;
    size_t off = 0;
    auto alloc = [&](size_t nfloats) { float* r = (float*)(ws + off); off += nfloats * sizeof(float); return r; };

    const size_t patN = (size_t)NB * NP * NH;
    const size_t restN = 3ull * NB * TC * NP + 2ull * NB * NP + (size_t)NCH * NB * TC * TC + (size_t)NB * TC * TC;
    float* pat;
    if (ws_size >= (patN + restN) * sizeof(float)) {
        pat = alloc(patN);
    } else {
        pat = (float*)d_in[1];  // fallback: mutate input in place (harness restores pristine copy per launch)
    }
    float* R0 = alloc((size_t)NB * TC * NP);
    float* q_g = alloc((size_t)NB * TC * NP);
    float* wc_g = alloc((size_t)NB * TC * NP);
    float* S_g = alloc((size_t)NB * NP);
    float* inr_g = alloc((size_t)NB * NP);
    float* G_all = alloc((size_t)NCH * NB * TC * TC);
    float* Beta = alloc((size_t)NB * TC * TC);

    kG<<<dim3(NCH, NB), 256, 0, stream>>>(x, G_all);
    kInit<<<dim3(4, NB), 256, 0, stream>>>(patin, pat, x, R0, inr_g);
    for (int c = 0; c < NCH; c++) {
        kInner<<<NB, 256, 0, stream>>>(R0, G_all, inr_g, q_g, wc_g, S_g, Beta, c);
        kOut<<<dim3(8, NB), 256, 0, stream>>>(pat, x, q_g, Beta, out, c);
        if (c + 1 < NCH) kMat<<<dim3(4, NB), 256, 0, stream>>>(pat, x, wc_g, S_g, R0, inr_g, c);
    }
}

// Round 3
// 3847.589 us; speedup vs baseline: 1.7937x; 1.0301x over previous
//
#include <hip/hip_runtime.h>
#include <math.h>

// GnrlPatSoftmaxRNN: chunked low-rank reformulation.
// pat_t = S_t[p]*pat_t0[p,:] + S_t[p]*sum_s v_s[p]*h_s[:], analytic norm
// n = sqrt(d^2 + 2 d pr raw + pr^2 ||h||^2) + 1e-10.
// R3: fix coalescing. All pat-streaming kernels use lanes-along-h
// (64 lanes x float4 = 1KB/instr). R1/R2 row-per-thread layout caused 3.5x
// write amplification (WRITE_SIZE 460MB vs 135MB ideal on kInit/kMat).
// hc/hn vectors live in REGISTERS (128 VGPR); per-row reductions via
// wave-synchronous LDS transpose (2-way bank aliasing = free per m136).

#define T_TOT 256
#define NB    64
#define NP    1024
#define NH    512
#define TC    16
#define NCH   (T_TOT / TC)
#define DECAYF 0.999f

__device__ __forceinline__ float dot4(float4 a, float4 b) {
    return a.x * b.x + a.y * b.y + a.z * b.z + a.w * b.w;
}

// ---------------------------------------------------------------- kG: Gram per chunk
__global__ __launch_bounds__(256) void kG(const float* __restrict__ x, float* __restrict__ G_all) {
    int c = blockIdx.x, b = blockIdx.y, tid = threadIdx.x;
    __shared__ float4 hs[TC][NH / 4 + 1];
    for (int idx = tid; idx < TC * (NH / 4); idx += 256) {
        int s = idx / (NH / 4), g = idx % (NH / 4);
        hs[s][g] = ((const float4*)x)[(size_t)((c * TC + s) * NB + b) * (NH / 4) + g];
    }
    __syncthreads();
    int si = tid / TC, ii = tid % TC;
    float acc = 0.f;
    for (int g = 0; g < NH / 4; g++) acc += dot4(hs[si][g], hs[ii][g]);
    G_all[(size_t)((c * NB + b) * TC + si) * TC + ii] = acc;
}

// ---------------------------------------------------------------- kPatR0: (optional copy) + nrm + R0 for chunk c
// lanes-along-h: lane owns float4 at h-idx lane (half A) and 64+lane (half B).
// grid (8, NB): 128 rows/block, 32 rows/wave.
__global__ __launch_bounds__(256) void kPatR0(const float* __restrict__ src, float* __restrict__ dst,
                                              const float* __restrict__ x, float* __restrict__ R0,
                                              float* __restrict__ inr_g, int c, int do_copy) {
    int b = blockIdx.y, tid = threadIdx.x;
    int w = tid >> 6, lane = tid & 63;
    int p0 = blockIdx.x * 128 + w * 32;
    __shared__ float scratch[4][16][65];  // per-wave transpose buffers
    const float4* x4 = (const float4*)x;
    float4 hnA[16], hnB[16];
#pragma unroll
    for (int s = 0; s < TC; s++) {
        size_t rb = (size_t)((c * TC + s) * NB + b) * (NH / 4);
        hnA[s] = x4[rb + lane];
        hnB[s] = x4[rb + 64 + lane];
    }
    const float4* s4 = (const float4*)src;
    float4* d4 = (float4*)dst;
    for (int r = 0; r < 32; r++) {
        int p = p0 + r;
        size_t rowb = (size_t)(b * NP + p) * (NH / 4);
        float4 pvA = s4[rowb + lane];
        float4 pvB = s4[rowb + 64 + lane];
        if (do_copy) { d4[rowb + lane] = pvA; d4[rowb + 64 + lane] = pvB; }
        float nrm = dot4(pvA, pvA) + dot4(pvB, pvB);
#pragma unroll
        for (int o = 32; o > 0; o >>= 1) nrm += __shfl_xor(nrm, o, 64);
        float inr = 1.0f / (sqrtf(nrm) + 1e-10f);
        float r0p[TC];
#pragma unroll
        for (int i = 0; i < TC; i++) r0p[i] = dot4(pvA, hnA[i]) + dot4(pvB, hnB[i]);
        // wave-synchronous transpose-reduce (no barrier needed within a wave)
#pragma unroll
        for (int i = 0; i < TC; i++) scratch[w][i][lane] = r0p[i];
        int v = lane & 15, cq = lane >> 4;
        float part = 0.f;
#pragma unroll
        for (int j = 0; j < 16; j++) part += scratch[w][v][cq * 16 + j];
        part += __shfl_xor(part, 16, 64);
        part += __shfl_xor(part, 32, 64);
        if (lane < 16) R0[(size_t)(b * TC + v) * NP + p] = part * inr;
        if (lane == 0) inr_g[b * NP + p] = inr;
    }
}

// ---------------------------------------------------------------- kInner: 16 sequential steps
__global__ __launch_bounds__(256, 1) void kInner(const float* __restrict__ R0, const float* __restrict__ G_all,
                                                 const float* __restrict__ inr_g, float* __restrict__ q_g,
                                                 float* __restrict__ wc_g, float* __restrict__ S_g,
                                                 float* __restrict__ Beta_g, int c) {
    int b = blockIdx.x, tid = threadIdx.x;
    __shared__ float Gs[TC * TC];
    __shared__ float redm[TC][4], reds[TC][4];
    __shared__ float betas[TC * TC];
    if (tid < TC * TC) {
        Gs[tid] = G_all[(size_t)(c * NB + b) * TC * TC + tid];
        betas[tid] = 0.f;
    }
    __syncthreads();
    const float* R0b = R0 + (size_t)b * TC * NP;
    float r0p[4][TC];
#pragma unroll
    for (int k = 0; k < 4; k++)
#pragma unroll
        for (int i = 0; i < TC; i++) r0p[k][i] = R0b[(size_t)i * NP + tid + 256 * k];

    float S[4] = {1.f, 1.f, 1.f, 1.f};
    float v[4][TC], q[4][TC];
    int wid = tid >> 6, lane = tid & 63;
    float raw[4];
#pragma unroll
    for (int i = 0; i < TC; i++) {
        float mymax = -1e30f;
#pragma unroll
        for (int k = 0; k < 4; k++) {
            float acc = r0p[k][i];
#pragma unroll
            for (int s = 0; s < i; s++) acc += v[k][s] * Gs[s * TC + i];
            raw[k] = S[k] * acc;
            mymax = fmaxf(mymax, raw[k]);
        }
#pragma unroll
        for (int o = 32; o > 0; o >>= 1) mymax = fmaxf(mymax, __shfl_xor(mymax, o, 64));
        if (lane == 0) redm[i][wid] = mymax;
        __syncthreads();
        float m = fmaxf(fmaxf(redm[i][0], redm[i][1]), fmaxf(redm[i][2], redm[i][3]));
        float hh = Gs[i * TC + i];
        float e[4], esum = 0.f;
#pragma unroll
        for (int k = 0; k < 4; k++) {
            float lg = (raw[k] >= 0.9f * m) ? (raw[k] / m) * 10.0f : 0.0f;
            e[k] = __expf(lg - 10.0f);
            esum += e[k];
        }
#pragma unroll
        for (int o = 32; o > 0; o >>= 1) esum += __shfl_xor(esum, o, 64);
        if (lane == 0) reds[i][wid] = esum;
        __syncthreads();
        float dinv = 1.0f / (reds[i][0] + reds[i][1] + reds[i][2] + reds[i][3]);
#pragma unroll
        for (int k = 0; k < 4; k++) {
            float pr = e[k] * dinv;
            q[k][i] = pr * S[k];
            float nn = sqrtf(DECAYF * DECAYF + 2.0f * DECAYF * pr * raw[k] + pr * pr * hh) + 1e-10f;
            v[k][i] = pr / (DECAYF * S[k]);
            S[k] = S[k] * (DECAYF / nn);
        }
    }
    // epilogue: q_g / wc_g now p-major ([b][p][i]) for vectorized consumers
#pragma unroll
    for (int k = 0; k < 4; k++) {
        int p = tid + 256 * k;
        float inr = inr_g[b * NP + p];
        float4* qdst = (float4*)(q_g + (size_t)(b * NP + p) * TC);
        float4* wdst = (float4*)(wc_g + (size_t)(b * NP + p) * TC);
#pragma unroll
        for (int j = 0; j < 4; j++) {
            float4 tq, tw;
            tq.x = q[k][4 * j + 0] * inr; tq.y = q[k][4 * j + 1] * inr;
            tq.z = q[k][4 * j + 2] * inr; tq.w = q[k][4 * j + 3] * inr;
            tw.x = S[k] * v[k][4 * j + 0]; tw.y = S[k] * v[k][4 * j + 1];
            tw.z = S[k] * v[k][4 * j + 2]; tw.w = S[k] * v[k][4 * j + 3];
            qdst[j] = tq; wdst[j] = tw;
        }
        S_g[b * NP + p] = S[k] * inr;
    }
#pragma unroll
    for (int i = 1; i < TC; i++) {
#pragma unroll
        for (int s = 0; s < i; s++) {
            float part = q[0][i] * v[0][s] + q[1][i] * v[1][s] + q[2][i] * v[2][s] + q[3][i] * v[3][s];
#pragma unroll
            for (int o = 32; o > 0; o >>= 1) part += __shfl_xor(part, o, 64);
            if (lane == 0) atomicAdd(&betas[i * TC + s], part);
        }
    }
    __syncthreads();
    if (tid < TC * TC) {
        int i = tid / TC, s = tid % TC;
        Beta_g[(size_t)b * TC * TC + tid] = (s < i) ? betas[tid] : 0.f;
    }
}

// ---------------------------------------------------------------- kOut: out = Q*pat_t0 + tril(Beta)*Hc
// grid (4, NB): block covers 128 h (lane -> float2), wave w -> i-set {4w..4w+3}
__global__ __launch_bounds__(256) void kOut(const float* __restrict__ pat, const float* __restrict__ x,
                                            const float* __restrict__ q_g, const float* __restrict__ Beta_g,
                                            float* __restrict__ out, int c) {
    int b = blockIdx.y, tid = threadIdx.x;
    int w = tid >> 6, lane = tid & 63;
    __shared__ __align__(16) float qsh[NP][16];  // 64 KB, p-major
    __shared__ float betash[TC * TC];
    const float4* qg4 = (const float4*)(q_g + (size_t)b * NP * TC);
    for (int idx = tid; idx < NP * 4; idx += 256) {
        float4 vv = qg4[idx];
        *(float4*)&qsh[idx >> 2][(idx & 3) * 4] = vv;
    }
    betash[tid] = Beta_g[(size_t)b * TC * TC + tid];
    __syncthreads();
    float accx[4] = {0.f, 0.f, 0.f, 0.f};
    float accy[4] = {0.f, 0.f, 0.f, 0.f};
    const float2* pat2 = (const float2*)pat;
    size_t hoff = (size_t)blockIdx.x * 64 + lane;  // float2 index within row
    for (int p = 0; p < NP; p++) {
        float2 pv = pat2[(size_t)(b * NP + p) * (NH / 2) + hoff];
        float4 qv = *(const float4*)&qsh[p][w * 4];  // broadcast read
        accx[0] += qv.x * pv.x; accy[0] += qv.x * pv.y;
        accx[1] += qv.y * pv.x; accy[1] += qv.y * pv.y;
        accx[2] += qv.z * pv.x; accy[2] += qv.z * pv.y;
        accx[3] += qv.w * pv.x; accy[3] += qv.w * pv.y;
    }
    const float2* x2 = (const float2*)x;
#pragma unroll
    for (int s = 0; s < TC; s++) {
        float2 xv = x2[(size_t)((c * TC + s) * NB + b) * (NH / 2) + hoff];
#pragma unroll
        for (int j = 0; j < 4; j++) {
            int i = w * 4 + j;
            if (s < i) { accx[j] += betash[i * TC + s] * xv.x; accy[j] += betash[i * TC + s] * xv.y; }
        }
    }
    float2* out2 = (float2*)out;
#pragma unroll
    for (int j = 0; j < 4; j++) {
        int i = w * 4 + j;
        float2 o; o.x = accx[j]; o.y = accy[j];
        out2[(size_t)((c * TC + i) * NB + b) * (NH / 2) + hoff] = o;
    }
}

// ---------------------------------------------------------------- kMat: pat := S*pat + Wc*Hc (store unnormalized)
// grid (8, NB): 128 rows/block, 32 rows/wave, lanes-along-h, hc in registers.
__global__ __launch_bounds__(256) void kMat(float* __restrict__ pat, const float* __restrict__ x,
                                            const float* __restrict__ wc_g, const float* __restrict__ S_g,
                                            int c) {
    int b = blockIdx.y, tid = threadIdx.x;
    int w = tid >> 6, lane = tid & 63;
    int pbase = blockIdx.x * 128;
    __shared__ __align__(16) float wcs[128][20];  // [r][0..15]=wc, [16]=Sf
    const float4* wcg4 = (const float4*)(wc_g + (size_t)(b * NP + pbase) * TC);
    for (int idx = tid; idx < 128 * 4; idx += 256) {
        float4 vv = wcg4[idx];
        *(float4*)&wcs[idx >> 2][(idx & 3) * 4] = vv;
    }
    for (int idx = tid; idx < 128; idx += 256) wcs[idx][16] = S_g[b * NP + pbase + idx];
    __syncthreads();
    const float4* x4 = (const float4*)x;
    float4 hcA[16], hcB[16];
#pragma unroll
    for (int s = 0; s < TC; s++) {
        size_t rb = (size_t)((c * TC + s) * NB + b) * (NH / 4);
        hcA[s] = x4[rb + lane];
        hcB[s] = x4[rb + 64 + lane];
    }
    float4* p4 = (float4*)pat;
    for (int r = 0; r < 32; r++) {
        int rr = w * 32 + r;
        int p = pbase + rr;
        size_t rowb = (size_t)(b * NP + p) * (NH / 4);
        float4 pvA = p4[rowb + lane];
        float4 pvB = p4[rowb + 64 + lane];
        float4 w0 = *(float4*)&wcs[rr][0];
        float4 w1 = *(float4*)&wcs[rr][4];
        float4 w2 = *(float4*)&wcs[rr][8];
        float4 w3 = *(float4*)&wcs[rr][12];
        float Sf = wcs[rr][16];
        float wcv[16] = {w0.x, w0.y, w0.z, w0.w, w1.x, w1.y, w1.z, w1.w,
                         w2.x, w2.y, w2.z, w2.w, w3.x, w3.y, w3.z, w3.w};
        float4 pnA, pnB;
        pnA.x = Sf * pvA.x; pnA.y = Sf * pvA.y; pnA.z = Sf * pvA.z; pnA.w = Sf * pvA.w;
        pnB.x = Sf * pvB.x; pnB.y = Sf * pvB.y; pnB.z = Sf * pvB.z; pnB.w = Sf * pvB.w;
#pragma unroll
        for (int s = 0; s < TC; s++) {
            pnA.x += wcv[s] * hcA[s].x; pnA.y += wcv[s] * hcA[s].y;
            pnA.z += wcv[s] * hcA[s].z; pnA.w += wcv[s] * hcA[s].w;
            pnB.x += wcv[s] * hcB[s].x; pnB.y += wcv[s] * hcB[s].y;
            pnB.z += wcv[s] * hcB[s].z; pnB.w += wcv[s] * hcB[s].w;
        }
        p4[rowb + lane] = pnA;
        p4[rowb + 64 + lane] = pnB;
    }
}

// ---------------------------------------------------------------- launch
extern "C" void kernel_launch(void* const* d_in, const int* in_sizes, int n_in,
                              void* d_out, int out_size, void* d_ws, size_t ws_size,
                              hipStream_t stream) {
    const float* x = (const float*)d_in[0];      // [T,B,H]
    const float* patin = (const float*)d_in[1];  // [B,P,H]
    float* out = (float*)d_out;                  // [T,B,H]

    char* ws = (char*)d_ws;
    size_t off = 0;
    auto alloc = [&](size_t nfloats) { float* r = (float*)(ws + off); off += nfloats * sizeof(float); return r; };

    const size_t patN = (size_t)NB * NP * NH;
    const size_t restN = 3ull * NB * TC * NP + 2ull * NB * NP + (size_t)NCH * NB * TC * TC + (size_t)NB * TC * TC;
    float* pat;
    if (ws_size >= (patN + restN) * sizeof(float)) {
        pat = alloc(patN);
    } else {
        pat = (float*)d_in[1];  // fallback: harness restores pristine copy per launch
    }
    float* R0 = alloc((size_t)NB * TC * NP);
    float* q_g = alloc((size_t)NB * TC * NP);
    float* wc_g = alloc((size_t)NB * TC * NP);
    float* S_g = alloc((size_t)NB * NP);
    float* inr_g = alloc((size_t)NB * NP);
    float* G_all = alloc((size_t)NCH * NB * TC * TC);
    float* Beta = alloc((size_t)NB * TC * TC);

    kG<<<dim3(NCH, NB), 256, 0, stream>>>(x, G_all);
    kPatR0<<<dim3(8, NB), 256, 0, stream>>>(patin, pat, x, R0, inr_g, 0, 1);  // copy + R0 for chunk 0
    for (int c = 0; c < NCH; c++) {
        kInner<<<NB, 256, 0, stream>>>(R0, G_all, inr_g, q_g, wc_g, S_g, Beta, c);
        kOut<<<dim3(4, NB), 256, 0, stream>>>(pat, x, q_g, Beta, out, c);
        if (c + 1 < NCH) {
            kMat<<<dim3(8, NB), 256, 0, stream>>>(pat, x, wc_g, S_g, c);
            kPatR0<<<dim3(8, NB), 256, 0, stream>>>(pat, pat, x, R0, inr_g, c + 1, 0);
        }
    }
}

// Round 4
// 3524.936 us; speedup vs baseline: 1.9579x; 1.0915x over previous
//
#include <hip/hip_runtime.h>
#include <math.h>

// GnrlPatSoftmaxRNN: chunked low-rank reformulation.
// pat_t = S_t[p]*pat_t0[p,:] + S_t[p]*sum_s v_s[p]*h_s[:], analytic norm
// n = sqrt(d^2 + 2 d pr raw + pr^2 ||h||^2) + 1e-10.
// R4: fuse kOut+kMat+kPatR0 into kStep -> pat streamed 1R+1W per chunk
// (was 3R+1W = 512 MB/chunk; R3 showed only ~half absorbed by L3).
// kStep sweep1: out-partials (per-block p-slice, per-wave i-slice);
// barrier; sweep2: update+write pat (L2-hot re-read) + r0 for next chunk.
// kOutRed sums 8 partials + tril(Beta)*x.

#define T_TOT 256
#define NB    64
#define NP    1024
#define NH    512
#define TC    16
#define NCH   (T_TOT / TC)
#define NPB   8           /* p-blocks in kStep: 128 rows each */
#define DECAYF 0.999f

__device__ __forceinline__ float dot4(float4 a, float4 b) {
    return a.x * b.x + a.y * b.y + a.z * b.z + a.w * b.w;
}
__device__ __forceinline__ void fma4(float4& acc, float s, float4 v) {
    acc.x += s * v.x; acc.y += s * v.y; acc.z += s * v.z; acc.w += s * v.w;
}

// ---------------------------------------------------------------- kG: Gram per chunk
__global__ __launch_bounds__(256) void kG(const float* __restrict__ x, float* __restrict__ G_all) {
    int c = blockIdx.x, b = blockIdx.y, tid = threadIdx.x;
    __shared__ float4 hs[TC][NH / 4 + 1];
    for (int idx = tid; idx < TC * (NH / 4); idx += 256) {
        int s = idx / (NH / 4), g = idx % (NH / 4);
        hs[s][g] = ((const float4*)x)[(size_t)((c * TC + s) * NB + b) * (NH / 4) + g];
    }
    __syncthreads();
    int si = tid / TC, ii = tid % TC;
    float acc = 0.f;
    for (int g = 0; g < NH / 4; g++) acc += dot4(hs[si][g], hs[ii][g]);
    G_all[(size_t)((c * NB + b) * TC + si) * TC + ii] = acc;
}

// ---------------------------------------------------------------- kPatR0: copy + nrm + R0 for chunk 0
// grid (16, NB): 64 rows/block, 16 rows/wave, lanes-along-h.
__global__ __launch_bounds__(256) void kPatR0(const float* __restrict__ src, float* __restrict__ dst,
                                              const float* __restrict__ x, float* __restrict__ R0,
                                              float* __restrict__ inr_g, int c, int do_copy) {
    int b = blockIdx.y, tid = threadIdx.x;
    int w = tid >> 6, lane = tid & 63;
    int p0 = blockIdx.x * 64 + w * 16;
    __shared__ float scratch[4][16][65];
    const float4* x4 = (const float4*)x;
    float4 hnA[16], hnB[16];
#pragma unroll
    for (int s = 0; s < TC; s++) {
        size_t rb = (size_t)((c * TC + s) * NB + b) * (NH / 4);
        hnA[s] = x4[rb + lane];
        hnB[s] = x4[rb + 64 + lane];
    }
    const float4* s4 = (const float4*)src;
    float4* d4 = (float4*)dst;
    for (int r = 0; r < 16; r++) {
        int p = p0 + r;
        size_t rowb = (size_t)(b * NP + p) * (NH / 4);
        float4 pvA = s4[rowb + lane];
        float4 pvB = s4[rowb + 64 + lane];
        if (do_copy) { d4[rowb + lane] = pvA; d4[rowb + 64 + lane] = pvB; }
        float nrm = dot4(pvA, pvA) + dot4(pvB, pvB);
#pragma unroll
        for (int o = 32; o > 0; o >>= 1) nrm += __shfl_xor(nrm, o, 64);
        float inr = 1.0f / (sqrtf(nrm) + 1e-10f);
        float r0p[TC];
#pragma unroll
        for (int i = 0; i < TC; i++) r0p[i] = dot4(pvA, hnA[i]) + dot4(pvB, hnB[i]);
#pragma unroll
        for (int i = 0; i < TC; i++) scratch[w][i][lane] = r0p[i];
        int v = lane & 15, cq = lane >> 4;
        float part = 0.f;
#pragma unroll
        for (int j = 0; j < 16; j++) part += scratch[w][v][cq * 16 + j];
        part += __shfl_xor(part, 16, 64);
        part += __shfl_xor(part, 32, 64);
        if (lane < 16) R0[(size_t)(b * TC + v) * NP + p] = part * inr;
        if (lane == 0) inr_g[b * NP + p] = inr;
    }
}

// ---------------------------------------------------------------- kInner: 16 sequential steps
__global__ __launch_bounds__(256, 1) void kInner(const float* __restrict__ R0, const float* __restrict__ G_all,
                                                 const float* __restrict__ inr_g, float* __restrict__ q_g,
                                                 float* __restrict__ wc_g, float* __restrict__ S_g,
                                                 float* __restrict__ Beta_g, int c) {
    int b = blockIdx.x, tid = threadIdx.x;
    __shared__ float Gs[TC * TC];
    __shared__ float redm[TC][4], reds[TC][4];
    __shared__ float betas[TC * TC];
    if (tid < TC * TC) {
        Gs[tid] = G_all[(size_t)(c * NB + b) * TC * TC + tid];
        betas[tid] = 0.f;
    }
    __syncthreads();
    const float* R0b = R0 + (size_t)b * TC * NP;
    float r0p[4][TC];
#pragma unroll
    for (int k = 0; k < 4; k++)
#pragma unroll
        for (int i = 0; i < TC; i++) r0p[k][i] = R0b[(size_t)i * NP + tid + 256 * k];

    float S[4] = {1.f, 1.f, 1.f, 1.f};
    float v[4][TC], q[4][TC];
    int wid = tid >> 6, lane = tid & 63;
    float raw[4];
#pragma unroll
    for (int i = 0; i < TC; i++) {
        float mymax = -1e30f;
#pragma unroll
        for (int k = 0; k < 4; k++) {
            float acc = r0p[k][i];
#pragma unroll
            for (int s = 0; s < i; s++) acc += v[k][s] * Gs[s * TC + i];
            raw[k] = S[k] * acc;
            mymax = fmaxf(mymax, raw[k]);
        }
#pragma unroll
        for (int o = 32; o > 0; o >>= 1) mymax = fmaxf(mymax, __shfl_xor(mymax, o, 64));
        if (lane == 0) redm[i][wid] = mymax;
        __syncthreads();
        float m = fmaxf(fmaxf(redm[i][0], redm[i][1]), fmaxf(redm[i][2], redm[i][3]));
        float hh = Gs[i * TC + i];
        float e[4], esum = 0.f;
#pragma unroll
        for (int k = 0; k < 4; k++) {
            float lg = (raw[k] >= 0.9f * m) ? (raw[k] / m) * 10.0f : 0.0f;
            e[k] = __expf(lg - 10.0f);
            esum += e[k];
        }
#pragma unroll
        for (int o = 32; o > 0; o >>= 1) esum += __shfl_xor(esum, o, 64);
        if (lane == 0) reds[i][wid] = esum;
        __syncthreads();
        float dinv = 1.0f / (reds[i][0] + reds[i][1] + reds[i][2] + reds[i][3]);
#pragma unroll
        for (int k = 0; k < 4; k++) {
            float pr = e[k] * dinv;
            q[k][i] = pr * S[k];
            float nn = sqrtf(DECAYF * DECAYF + 2.0f * DECAYF * pr * raw[k] + pr * pr * hh) + 1e-10f;
            v[k][i] = pr / (DECAYF * S[k]);
            S[k] = S[k] * (DECAYF / nn);
        }
    }
#pragma unroll
    for (int k = 0; k < 4; k++) {
        int p = tid + 256 * k;
        float inr = inr_g[b * NP + p];
        float4* qdst = (float4*)(q_g + (size_t)(b * NP + p) * TC);
        float4* wdst = (float4*)(wc_g + (size_t)(b * NP + p) * TC);
#pragma unroll
        for (int j = 0; j < 4; j++) {
            float4 tq, tw;
            tq.x = q[k][4 * j + 0] * inr; tq.y = q[k][4 * j + 1] * inr;
            tq.z = q[k][4 * j + 2] * inr; tq.w = q[k][4 * j + 3] * inr;
            tw.x = S[k] * v[k][4 * j + 0]; tw.y = S[k] * v[k][4 * j + 1];
            tw.z = S[k] * v[k][4 * j + 2]; tw.w = S[k] * v[k][4 * j + 3];
            qdst[j] = tq; wdst[j] = tw;
        }
        S_g[b * NP + p] = S[k] * inr;
    }
#pragma unroll
    for (int i = 1; i < TC; i++) {
#pragma unroll
        for (int s = 0; s < i; s++) {
            float part = q[0][i] * v[0][s] + q[1][i] * v[1][s] + q[2][i] * v[2][s] + q[3][i] * v[3][s];
#pragma unroll
            for (int o = 32; o > 0; o >>= 1) part += __shfl_xor(part, o, 64);
            if (lane == 0) atomicAdd(&betas[i * TC + s], part);
        }
    }
    __syncthreads();
    if (tid < TC * TC) {
        int i = tid / TC, s = tid % TC;
        Beta_g[(size_t)b * TC * TC + tid] = (s < i) ? betas[tid] : 0.f;
    }
}

// ---------------------------------------------------------------- kStep: fused out-partials + update + r0
// grid (NPB, NB), block 256. Block owns 128 pat rows (pbase..pbase+127).
// Sweep1: every wave reads all 128 rows, accumulates out-partials for its
//   4 i-values (i = 4w..4w+3), writes partials to `part`.
// Barrier (no row is written before all waves have read it).
// Sweep2 (do_upd): wave w re-reads its 32 rows (L2-hot), pn = Sf*pv + Wc*Hc,
//   writes pat, computes nrm + r0 vs next chunk h (hn in LDS).
__global__ __launch_bounds__(256) void kStep(float* __restrict__ pat, const float* __restrict__ x,
                                             const float* __restrict__ q_g, const float* __restrict__ wc_g,
                                             const float* __restrict__ S_g, float* __restrict__ R0,
                                             float* __restrict__ inr_g, float* __restrict__ part,
                                             int c, int do_upd) {
    int b = blockIdx.y, tid = threadIdx.x;
    int w = tid >> 6, lane = tid & 63;
    int pbase = blockIdx.x * 128;
    __shared__ float4 hn[TC][NH / 4];            // 32 KB: next-chunk h
    __shared__ __align__(16) float wcs[128][20]; // 10 KB: wc(16)+Sf
    __shared__ float scratch[4][16][65];         // 16.6 KB: r0 transpose-reduce

    if (do_upd) {
        for (int idx = tid; idx < TC * (NH / 4); idx += 256) {
            int s = idx / (NH / 4), g = idx % (NH / 4);
            hn[s][g] = ((const float4*)x)[(size_t)(((c + 1) * TC + s) * NB + b) * (NH / 4) + g];
        }
        const float4* wcg4 = (const float4*)(wc_g + (size_t)(b * NP + pbase) * TC);
        for (int idx = tid; idx < 128 * 4; idx += 256) {
            float4 vv = wcg4[idx];
            *(float4*)&wcs[idx >> 2][(idx & 3) * 4] = vv;
        }
        for (int idx = tid; idx < 128; idx += 256) wcs[idx][16] = S_g[b * NP + pbase + idx];
    }

    // ---- sweep 1: out partials ----
    const float4* p4c = (const float4*)pat;
    float4 accA[4], accB[4];
#pragma unroll
    for (int j = 0; j < 4; j++) { accA[j] = make_float4(0.f, 0.f, 0.f, 0.f); accB[j] = make_float4(0.f, 0.f, 0.f, 0.f); }
    for (int r = 0; r < 128; r++) {
        int p = pbase + r;
        size_t rowb = (size_t)(b * NP + p) * (NH / 4);
        float4 pvA = p4c[rowb + lane];
        float4 pvB = p4c[rowb + 64 + lane];
        float4 qv = *(const float4*)(q_g + (size_t)(b * NP + p) * TC + w * 4);
        fma4(accA[0], qv.x, pvA); fma4(accB[0], qv.x, pvB);
        fma4(accA[1], qv.y, pvA); fma4(accB[1], qv.y, pvB);
        fma4(accA[2], qv.z, pvA); fma4(accB[2], qv.z, pvB);
        fma4(accA[3], qv.w, pvA); fma4(accB[3], qv.w, pvB);
    }
    float4* part4 = (float4*)part;
#pragma unroll
    for (int j = 0; j < 4; j++) {
        size_t pb = ((((size_t)blockIdx.x * NB + b) * TC) + (w * 4 + j)) * (NH / 4);
        part4[pb + lane] = accA[j];
        part4[pb + 64 + lane] = accB[j];
    }

    __syncthreads();  // all reads of pat rows done; LDS staging visible
    if (!do_upd) return;

    // ---- sweep 2: update + write + r0 ----
    const float4* x4 = (const float4*)x;
    float4 hcA[16], hcB[16];
#pragma unroll
    for (int s = 0; s < TC; s++) {
        size_t rb = (size_t)((c * TC + s) * NB + b) * (NH / 4);
        hcA[s] = x4[rb + lane];
        hcB[s] = x4[rb + 64 + lane];
    }
    float4* p4 = (float4*)pat;
    for (int r = 0; r < 32; r++) {
        int rr = w * 32 + r;
        int p = pbase + rr;
        size_t rowb = (size_t)(b * NP + p) * (NH / 4);
        float4 pvA = p4[rowb + lane];
        float4 pvB = p4[rowb + 64 + lane];
        float4 w0 = *(float4*)&wcs[rr][0];
        float4 w1 = *(float4*)&wcs[rr][4];
        float4 w2 = *(float4*)&wcs[rr][8];
        float4 w3 = *(float4*)&wcs[rr][12];
        float Sf = wcs[rr][16];
        float wcv[16] = {w0.x, w0.y, w0.z, w0.w, w1.x, w1.y, w1.z, w1.w,
                         w2.x, w2.y, w2.z, w2.w, w3.x, w3.y, w3.z, w3.w};
        float4 pnA, pnB;
        pnA.x = Sf * pvA.x; pnA.y = Sf * pvA.y; pnA.z = Sf * pvA.z; pnA.w = Sf * pvA.w;
        pnB.x = Sf * pvB.x; pnB.y = Sf * pvB.y; pnB.z = Sf * pvB.z; pnB.w = Sf * pvB.w;
#pragma unroll
        for (int s = 0; s < TC; s++) {
            fma4(pnA, wcv[s], hcA[s]);
            fma4(pnB, wcv[s], hcB[s]);
        }
        p4[rowb + lane] = pnA;
        p4[rowb + 64 + lane] = pnB;
        float nrm = dot4(pnA, pnA) + dot4(pnB, pnB);
#pragma unroll
        for (int o = 32; o > 0; o >>= 1) nrm += __shfl_xor(nrm, o, 64);
        float inr = 1.0f / (sqrtf(nrm) + 1e-10f);
        float r0p[TC];
#pragma unroll
        for (int i = 0; i < TC; i++) r0p[i] = dot4(pnA, hn[i][lane]) + dot4(pnB, hn[i][64 + lane]);
#pragma unroll
        for (int i = 0; i < TC; i++) scratch[w][i][lane] = r0p[i];
        int v = lane & 15, cq = lane >> 4;
        float ps = 0.f;
#pragma unroll
        for (int j = 0; j < 16; j++) ps += scratch[w][v][cq * 16 + j];
        ps += __shfl_xor(ps, 16, 64);
        ps += __shfl_xor(ps, 32, 64);
        if (lane < 16) R0[(size_t)(b * TC + v) * NP + p] = ps * inr;
        if (lane == 0) inr_g[b * NP + p] = inr;
    }
}

// ---------------------------------------------------------------- kOutRed: out = sum(partials) + tril(Beta)*Hc
// grid (4, NB): wave w of block iq handles i = iq*4+w; lane covers h slots lane, 64+lane (float4)
__global__ __launch_bounds__(256) void kOutRed(const float* __restrict__ part, const float* __restrict__ x,
                                               const float* __restrict__ Beta_g, float* __restrict__ out, int c) {
    int b = blockIdx.y, iq = blockIdx.x, tid = threadIdx.x;
    int w = tid >> 6, lane = tid & 63;
    int i = iq * 4 + w;
    const float4* part4 = (const float4*)part;
    float4 sumA = make_float4(0.f, 0.f, 0.f, 0.f), sumB = make_float4(0.f, 0.f, 0.f, 0.f);
#pragma unroll
    for (int blk = 0; blk < NPB; blk++) {
        size_t base = ((((size_t)blk * NB + b) * TC) + i) * (NH / 4);
        float4 a = part4[base + lane];
        float4 bb = part4[base + 64 + lane];
        sumA.x += a.x; sumA.y += a.y; sumA.z += a.z; sumA.w += a.w;
        sumB.x += bb.x; sumB.y += bb.y; sumB.z += bb.z; sumB.w += bb.w;
    }
    const float4* x4 = (const float4*)x;
    const float* Bb = Beta_g + (size_t)b * TC * TC + i * TC;
#pragma unroll
    for (int s = 0; s < TC - 1; s++) {
        if (s < i) {
            float beta = Bb[s];
            size_t rb = (size_t)((c * TC + s) * NB + b) * (NH / 4);
            fma4(sumA, beta, x4[rb + lane]);
            fma4(sumB, beta, x4[rb + 64 + lane]);
        }
    }
    size_t ob = (size_t)((c * TC + i) * NB + b) * (NH / 4);
    ((float4*)out)[ob + lane] = sumA;
    ((float4*)out)[ob + 64 + lane] = sumB;
}

// ---------------------------------------------------------------- launch
extern "C" void kernel_launch(void* const* d_in, const int* in_sizes, int n_in,
                              void* d_out, int out_size, void* d_ws, size_t ws_size,
                              hipStream_t stream) {
    const float* x = (const float*)d_in[0];      // [T,B,H]
    const float* patin = (const float*)d_in[1];  // [B,P,H]
    float* out = (float*)d_out;                  // [T,B,H]

    char* ws = (char*)d_ws;
    size_t off = 0;
    auto alloc = [&](size_t nfloats) { float* r = (float*)(ws + off); off += nfloats * sizeof(float); return r; };

    // small buffers first so they always fit; pat falls back to in-place if ws is tight
    float* R0 = alloc((size_t)NB * TC * NP);
    float* q_g = alloc((size_t)NB * TC * NP);
    float* wc_g = alloc((size_t)NB * TC * NP);
    float* S_g = alloc((size_t)NB * NP);
    float* inr_g = alloc((size_t)NB * NP);
    float* G_all = alloc((size_t)NCH * NB * TC * TC);
    float* Beta = alloc((size_t)NB * TC * TC);
    float* part = alloc((size_t)NPB * NB * TC * NH);
    const size_t patN = (size_t)NB * NP * NH;
    float* pat;
    if (ws_size >= off + patN * sizeof(float)) {
        pat = alloc(patN);
    } else {
        pat = (float*)d_in[1];  // in-place fallback: harness restores pristine input per launch
    }

    kG<<<dim3(NCH, NB), 256, 0, stream>>>(x, G_all);
    kPatR0<<<dim3(16, NB), 256, 0, stream>>>(patin, pat, x, R0, inr_g, 0, 1);
    for (int c = 0; c < NCH; c++) {
        kInner<<<NB, 256, 0, stream>>>(R0, G_all, inr_g, q_g, wc_g, S_g, Beta, c);
        kStep<<<dim3(NPB, NB), 256, 0, stream>>>(pat, x, q_g, wc_g, S_g, R0, inr_g, part, c, (c + 1 < NCH) ? 1 : 0);
        kOutRed<<<dim3(4, NB), 256, 0, stream>>>(part, x, Beta, out, c);
    }
}